// Round 7
// baseline (542.038 us; speedup 1.0000x reference)
//
#include <hip/hip_runtime.h>
#include <math.h>

#define C_CH 512
#define T_LEN 4096
#define NTT 32            // t tiles of 128

typedef unsigned short bf16_t;
typedef short bf16x8 __attribute__((ext_vector_type(8)));
typedef float f32x4 __attribute__((ext_vector_type(4)));

__device__ inline bf16_t f2bf(float x) {
  unsigned u = __float_as_uint(x);
  return (bf16_t)((u + 0x7FFF + ((u >> 16) & 1)) >> 16);
}
__device__ inline float bf2f(bf16_t h) { return __uint_as_float(((unsigned)h) << 16); }
__device__ inline float loadv(const float* p, int i) { return p[i]; }
__device__ inline float loadv(const bf16_t* p, int i) { return bf2f(p[i]); }

// ---- ws float offsets ----
#define OFF_FILT 0
#define OFF_S1   64
#define OFF_S2   576
#define OFF_S3   2624
#define OFF_WFP  4096                  // 8 * 512*512 f32 partials
#define OFF_WP1  2101248               // 7*512*512 bf16
#define OFF_WPF  3018752               // 512*512 bf16
#define OFF_H1   3149824               // 4*512*4096 bf16 (NCH)
#define OFF_H2   7344128
#define OFF_H3   11538432

__device__ double i0d(double x) {
  double t = 0.5 * x, t2 = t * t;
  double term = 1.0, sum = 1.0;
  for (int k = 1; k < 60; ++k) {
    term *= t2 / ((double)k * (double)k);
    sum += term;
    if (term < 1e-17 * sum) break;
  }
  return sum;
}

__global__ __launch_bounds__(256) void init_consts(
    const float* __restrict__ v1, const float* __restrict__ g1,
    const float* __restrict__ v2, const float* __restrict__ g2,
    const float* __restrict__ v3, const float* __restrict__ g3,
    float* __restrict__ ws)
{
  int blk = blockIdx.x;
  if (blk == 3072) {
    if (threadIdx.x == 0) {
      double beta = 0.1102 * (2.285 * 5.0 * M_PI * 1.2 + 7.95 - 8.7);
      double ib = i0d(beta);
      double f[12]; double s = 0.0;
      for (int n = 0; n < 12; ++n) {
        double r = ((double)n - 5.5) / 5.5;
        double w = i0d(beta * sqrt(fmax(0.0, 1.0 - r * r))) / ib;
        double tt = ((double)n - 5.5) * 0.5;
        double sc = sin(M_PI * tt) / (M_PI * tt);
        f[n] = 0.5 * w * sc;
        s += f[n];
      }
      for (int n = 0; n < 12; ++n) ws[OFF_FILT + n] = (float)(f[n] / s);
    }
    return;
  }
  const float* v; const float* g; int len; float* out;
  if (blk < 512)       { v = v1 + (size_t)blk * 3584;        g = g1 + blk;        len = 3584; out = ws + OFF_S1 + blk; }
  else if (blk < 2560) { int m = blk - 512;  v = v2 + (size_t)m * 512;  g = g2 + m; len = 512;  out = ws + OFF_S2 + m; }
  else                 { int m = blk - 2560; v = v3 + (size_t)m * 2048; g = g3 + m; len = 2048; out = ws + OFF_S3 + m; }
  float s = 0.f;
  for (int i = threadIdx.x; i < len; i += 256) { float x = v[i]; s = fmaf(x, x, s); }
  #pragma unroll
  for (int off = 32; off > 0; off >>= 1) s += __shfl_down(s, off);
  __shared__ float red[4];
  int lane = threadIdx.x & 63, w = threadIdx.x >> 6;
  if (lane == 0) red[w] = s;
  __syncthreads();
  if (threadIdx.x == 0) {
    float tot = red[0] + red[1] + red[2] + red[3];
    *out = g[0] / sqrtf(tot);
  }
}

// split-K weight fusion
__global__ __launch_bounds__(256) void fuse_w(
    const float* __restrict__ v2, const float* __restrict__ v3,
    float* __restrict__ ws)
{
  const float* s2 = ws + OFF_S2;
  float* wfp = ws + OFF_WFP;
  __shared__ float a[32][68];
  __shared__ float bsh[32][68];
  int i0 = blockIdx.x * 64, o0 = blockIdx.y * 64;
  int mbase = blockIdx.z * 256;
  int tid = threadIdx.x;
  int ii = tid & 15, io = tid >> 4;
  float acc[4][4] = {};
  for (int m0 = mbase; m0 < mbase + 256; m0 += 32) {
    for (int idx = tid; idx < 2048; idx += 256) {
      int o_l = idx >> 5, mm = idx & 31;
      a[mm][o_l] = v3[(size_t)(o0 + o_l) * 2048 + m0 + mm];
    }
    for (int idx = tid; idx < 2048; idx += 256) {
      int mm = idx >> 6, i_l = idx & 63;
      bsh[mm][i_l] = v2[(size_t)(m0 + mm) * 512 + i0 + i_l] * s2[m0 + mm];
    }
    __syncthreads();
    #pragma unroll 8
    for (int mm = 0; mm < 32; ++mm) {
      float4 av = *(const float4*)&a[mm][io * 4];
      float4 bv = *(const float4*)&bsh[mm][ii * 4];
      float ar[4] = {av.x, av.y, av.z, av.w};
      float br[4] = {bv.x, bv.y, bv.z, bv.w};
      #pragma unroll
      for (int p = 0; p < 4; ++p)
        #pragma unroll
        for (int q = 0; q < 4; ++q)
          acc[p][q] = fmaf(ar[p], br[q], acc[p][q]);
    }
    __syncthreads();
  }
  float* wout = wfp + (size_t)blockIdx.z * 512 * 512;
  #pragma unroll
  for (int p = 0; p < 4; ++p) {
    int o = o0 + io * 4 + p;
    float4 r;
    r.x = acc[p][0]; r.y = acc[p][1]; r.z = acc[p][2]; r.w = acc[p][3];
    *(float4*)&wout[(size_t)o * 512 + i0 + ii * 4] = r;
  }
}

__global__ __launch_bounds__(256) void wfpack(
    const float* __restrict__ wfp, const float* __restrict__ s3,
    bf16_t* __restrict__ wpf)
{
  int idx = blockIdx.x * 256 + threadIdx.x;
  int o = idx >> 9;
  float s = 0.f;
  #pragma unroll
  for (int kc = 0; kc < 8; ++kc) s += wfp[(size_t)kc * 262144 + idx];
  wpf[idx] = f2bf(s * s3[o]);
}

// wp1[tap][o][i] = bf16(v1[o][i][tap] * s1[o]); thread per (o,i), taps contiguous
__global__ __launch_bounds__(256) void wprep1(
    const float* __restrict__ v1, const float* __restrict__ s1w,
    bf16_t* __restrict__ wp)
{
  int idx = blockIdx.x * 256 + threadIdx.x;   // 512*512
  int o = idx >> 9;
  float s = s1w[o];
  const float* vp = v1 + (size_t)idx * 7;
  #pragma unroll
  for (int tap = 0; tap < 7; ++tap)
    wp[(size_t)tap * 262144 + idx] = f2bf(vp[tap] * s);
}

// fused act1d: upsample x2 (edge pad) -> snake_beta -> downsample x2 (round-5 proven)
template <typename T>
__global__ __launch_bounds__(256) void act_kernel(
    const T* __restrict__ src, bf16_t* __restrict__ dst,
    const float* __restrict__ alpha, const float* __restrict__ beta,
    const float* __restrict__ filt_g)
{
  __shared__ float xs[522];
  __shared__ float ys[1034];
  __shared__ float F[12];
  int t0 = blockIdx.x * 512;
  int c = blockIdx.y;
  int b = blockIdx.z;
  const T* row = src + ((size_t)b * C_CH + c) * T_LEN;
  bf16_t* orow = dst + ((size_t)b * C_CH + c) * T_LEN;
  int tid = threadIdx.x;
  if (tid < 12) F[tid] = filt_g[tid];
  float ea = __expf(alpha[c]);
  float ibv = 1.0f / (__expf(beta[c]) + 1e-9f);
  for (int i = tid; i < 522; i += 256) {
    int g = t0 - 5 + i;
    g = min(max(g, 0), T_LEN - 1);
    xs[i] = loadv(row, g);
  }
  __syncthreads();
  for (int m = tid; m < 1034; m += 256) {
    int n = 2 * t0 - 5 + m;
    n = min(max(n, 0), 2 * T_LEN - 1);
    int tp = n >> 1;
    int base = tp - t0;
    float s = 0.f;
    if (n & 1) {
      #pragma unroll
      for (int u = 0; u < 6; ++u) s = fmaf(xs[base + 3 + u], F[10 - 2 * u], s);
    } else {
      #pragma unroll
      for (int u = 0; u < 6; ++u) s = fmaf(xs[base + 2 + u], F[11 - 2 * u], s);
    }
    float y = 2.f * s;
    float sn = __sinf(y * ea);
    ys[m] = fmaf(ibv * sn, sn, y);
  }
  __syncthreads();
  for (int tl = tid; tl < 512; tl += 256) {
    float h = 0.f;
    #pragma unroll
    for (int k = 0; k < 12; ++k) h = fmaf(F[k], ys[2 * tl + k], h);
    orow[t0 + tl] = f2bf(h);
  }
}

// conv K=7, 512->512, zero-pad-3, MFMA 16x16x32 bf16, NCH I/O.
// Block tile 64(o) x 128(t); 4 waves, each 64o x 32t (m4 x n2 frags).
// Grid (32,8,4)=1024 blocks -> 4 blocks/CU, 16 waves/CU.
__global__ __launch_bounds__(256, 4) void conv7_mfma(
    const bf16_t* __restrict__ src, const bf16_t* __restrict__ wp,
    bf16_t* __restrict__ dst)
{
  __shared__ __align__(16) bf16_t Xs[144 * 64];
  const int t0 = blockIdx.x * 128;
  const int o0 = blockIdx.y * 64;
  const int b  = blockIdx.z;
  const int tid = threadIdx.x;
  const int wave = tid >> 6;
  const int lane = tid & 63;
  const int l15 = lane & 15, lhi = lane >> 4;
  const int trow0 = wave * 32;
  f32x4 acc[4][2];
  #pragma unroll
  for (int m = 0; m < 4; ++m)
    #pragma unroll
    for (int n = 0; n < 2; ++n)
      acc[m][n] = (f32x4){0.f, 0.f, 0.f, 0.f};

  const bf16_t* xg = src + (size_t)b * C_CH * T_LEN;

  for (int cb = 0; cb < 512; cb += 64) {
    __syncthreads();
    // stage x[t0-8 .. t0+136) x 64ch, transposed [t][ch], XOR swizzle
    for (int u = tid; u < 18 * 64; u += 256) {
      int cc = u & 63;
      int ro = u >> 6;
      int gt0 = t0 - 8 + ro * 8;
      const bf16_t* gp = xg + (size_t)(cb + cc) * T_LEN + gt0;
      bf16_t vals[8];
      if (gt0 >= 0 && gt0 + 8 <= T_LEN) {
        bf16x8 v = *(const bf16x8*)gp;
        #pragma unroll
        for (int i = 0; i < 8; ++i) vals[i] = (bf16_t)v[i];
      } else {
        #pragma unroll
        for (int i = 0; i < 8; ++i) {
          int gt = gt0 + i;
          vals[i] = (gt >= 0 && gt < T_LEN) ? gp[i] : (bf16_t)0;
        }
      }
      #pragma unroll
      for (int i = 0; i < 8; ++i) {
        int rl = ro * 8 + i;
        int byteoff = rl * 128 + ((cc * 2) ^ ((rl & 7) << 4));
        *(bf16_t*)((char*)Xs + byteoff) = vals[i];
      }
    }
    __syncthreads();
    #pragma unroll
    for (int tap = 0; tap < 7; ++tap) {
      #pragma unroll
      for (int ks = 0; ks < 2; ++ks) {
        const int chcol = ks * 32 + lhi * 8;
        bf16x8 a[4];
        #pragma unroll
        for (int m = 0; m < 4; ++m) {
          int o = o0 + m * 16 + l15;
          a[m] = *(const bf16x8*)(wp + ((size_t)(tap * 512 + o) * 512) + cb + chcol);
        }
        bf16x8 bfr[2];
        #pragma unroll
        for (int n = 0; n < 2; ++n) {
          int row = trow0 + n * 16 + l15 + tap + 5;
          int byteoff = row * 128 + ((chcol * 2) ^ ((row & 7) << 4));
          bfr[n] = *(const bf16x8*)((const char*)Xs + byteoff);
        }
        #pragma unroll
        for (int m = 0; m < 4; ++m)
          #pragma unroll
          for (int n = 0; n < 2; ++n)
            acc[m][n] = __builtin_amdgcn_mfma_f32_16x16x32_bf16(a[m], bfr[n], acc[m][n], 0, 0, 0);
      }
    }
  }
  bf16_t* drow = dst + (size_t)b * C_CH * T_LEN;
  #pragma unroll
  for (int m = 0; m < 4; ++m)
    #pragma unroll
    for (int n = 0; n < 2; ++n) {
      int t = t0 + trow0 + n * 16 + l15;
      #pragma unroll
      for (int r = 0; r < 4; ++r) {
        int o = o0 + m * 16 + lhi * 4 + r;
        drow[(size_t)o * T_LEN + t] = f2bf(acc[m][n][r]);
      }
    }
}

// out = x + wf @ h (1x1 512->512), NCH I/O, residual f32 out.
// Same tiling as conv7: 64o x 128t per block, 4 waves, grid (32,8,4).
__global__ __launch_bounds__(256, 4) void gemm_mfma(
    const bf16_t* __restrict__ src, const bf16_t* __restrict__ wp,
    const float* __restrict__ x, float* __restrict__ out)
{
  __shared__ __align__(16) bf16_t Xs[128 * 64];
  const int t0 = blockIdx.x * 128;
  const int o0 = blockIdx.y * 64;
  const int b  = blockIdx.z;
  const int tid = threadIdx.x;
  const int wave = tid >> 6;
  const int lane = tid & 63;
  const int l15 = lane & 15, lhi = lane >> 4;
  const int trow0 = wave * 32;
  f32x4 acc[4][2];
  #pragma unroll
  for (int m = 0; m < 4; ++m)
    #pragma unroll
    for (int n = 0; n < 2; ++n)
      acc[m][n] = (f32x4){0.f, 0.f, 0.f, 0.f};

  const bf16_t* xg = src + (size_t)b * C_CH * T_LEN;

  for (int cb = 0; cb < 512; cb += 64) {
    __syncthreads();
    for (int u = tid; u < 16 * 64; u += 256) {
      int cc = u & 63;
      int ro = u >> 6;
      const bf16_t* gp = xg + (size_t)(cb + cc) * T_LEN + t0 + ro * 8;
      bf16x8 v = *(const bf16x8*)gp;
      #pragma unroll
      for (int i = 0; i < 8; ++i) {
        int rl = ro * 8 + i;
        int byteoff = rl * 128 + ((cc * 2) ^ ((rl & 7) << 4));
        *(bf16_t*)((char*)Xs + byteoff) = (bf16_t)v[i];
      }
    }
    __syncthreads();
    #pragma unroll
    for (int ks = 0; ks < 2; ++ks) {
      const int chcol = ks * 32 + lhi * 8;
      bf16x8 a[4];
      #pragma unroll
      for (int m = 0; m < 4; ++m) {
        int o = o0 + m * 16 + l15;
        a[m] = *(const bf16x8*)(wp + (size_t)o * 512 + cb + chcol);
      }
      bf16x8 bfr[2];
      #pragma unroll
      for (int n = 0; n < 2; ++n) {
        int row = trow0 + n * 16 + l15;
        int byteoff = row * 128 + ((chcol * 2) ^ ((row & 7) << 4));
        bfr[n] = *(const bf16x8*)((const char*)Xs + byteoff);
      }
      #pragma unroll
      for (int m = 0; m < 4; ++m)
        #pragma unroll
        for (int n = 0; n < 2; ++n)
          acc[m][n] = __builtin_amdgcn_mfma_f32_16x16x32_bf16(a[m], bfr[n], acc[m][n], 0, 0, 0);
    }
  }
  #pragma unroll
  for (int m = 0; m < 4; ++m)
    #pragma unroll
    for (int n = 0; n < 2; ++n) {
      int t = t0 + trow0 + n * 16 + l15;
      #pragma unroll
      for (int r = 0; r < 4; ++r) {
        int o = o0 + m * 16 + lhi * 4 + r;
        size_t off = ((size_t)b * C_CH + o) * T_LEN + t;
        out[off] = x[off] + acc[m][n][r];
      }
    }
}

extern "C" void kernel_launch(void* const* d_in, const int* in_sizes, int n_in,
                              void* d_out, int out_size, void* d_ws, size_t ws_size,
                              hipStream_t stream) {
  const float* x  = (const float*)d_in[0];
  const float* a1 = (const float*)d_in[1];
  const float* b1 = (const float*)d_in[2];
  const float* v1 = (const float*)d_in[3];
  const float* g1 = (const float*)d_in[4];
  const float* a2 = (const float*)d_in[5];
  const float* b2 = (const float*)d_in[6];
  const float* v2 = (const float*)d_in[7];
  const float* g2 = (const float*)d_in[8];
  const float* v3 = (const float*)d_in[9];
  const float* g3 = (const float*)d_in[10];
  float* out = (float*)d_out;
  float* ws  = (float*)d_ws;
  bf16_t* wp1 = (bf16_t*)(ws + OFF_WP1);
  bf16_t* wpf = (bf16_t*)(ws + OFF_WPF);
  bf16_t* h1  = (bf16_t*)(ws + OFF_H1);
  bf16_t* h2  = (bf16_t*)(ws + OFF_H2);
  bf16_t* h3  = (bf16_t*)(ws + OFF_H3);

  init_consts<<<3073, 256, 0, stream>>>(v1, g1, v2, g2, v3, g3, ws);
  fuse_w<<<dim3(8, 8, 8), 256, 0, stream>>>(v2, v3, ws);
  wfpack<<<1024, 256, 0, stream>>>(ws + OFF_WFP, ws + OFF_S3, wpf);
  wprep1<<<1024, 256, 0, stream>>>(v1, ws + OFF_S1, wp1);
  act_kernel<float><<<dim3(8, 512, 4), 256, 0, stream>>>(x, h1, a1, b1, ws + OFF_FILT);
  conv7_mfma<<<dim3(NTT, 8, 4), 256, 0, stream>>>(h1, wp1, h2);
  act_kernel<bf16_t><<<dim3(8, 512, 4), 256, 0, stream>>>(h2, h3, a2, b2, ws + OFF_FILT);
  gemm_mfma<<<dim3(NTT, 8, 4), 256, 0, stream>>>(h3, wpf, x, out);
}

// Round 9
// 327.477 us; speedup vs baseline: 1.6552x; 1.6552x over previous
//
#include <hip/hip_runtime.h>
#include <math.h>

#define C_CH 512
#define T_LEN 4096

typedef unsigned short bf16_t;
typedef short bf16x8 __attribute__((ext_vector_type(8)));
typedef float f32x4 __attribute__((ext_vector_type(4)));

__device__ inline bf16_t f2bf(float x) {
  unsigned u = __float_as_uint(x);
  return (bf16_t)((u + 0x7FFF + ((u >> 16) & 1)) >> 16);
}
__device__ inline float bf2f(bf16_t h) { return __uint_as_float(((unsigned)h) << 16); }
__device__ inline float loadv(const float* p, int i) { return p[i]; }
__device__ inline float loadv(const bf16_t* p, int i) { return bf2f(p[i]); }

// ---- ws float offsets ----
#define OFF_FILT 0
#define OFF_S1   64
#define OFF_S2   576
#define OFF_S3   2624
#define OFF_WFP  4096                  // 8 * 512*512 f32 partials
#define OFF_WP1  2101248               // 7*512*512 bf16 (frag-packed)
#define OFF_WPF  3018752               // 512*512 bf16 (frag-packed)
#define OFF_H1   3149824               // 4*512*4096 bf16 (NCH)
#define OFF_H2   7344128
#define OFF_H3   11538432

__device__ double i0d(double x) {
  double t = 0.5 * x, t2 = t * t;
  double term = 1.0, sum = 1.0;
  for (int k = 1; k < 60; ++k) {
    term *= t2 / ((double)k * (double)k);
    sum += term;
    if (term < 1e-17 * sum) break;
  }
  return sum;
}

__global__ __launch_bounds__(256) void init_consts(
    const float* __restrict__ v1, const float* __restrict__ g1,
    const float* __restrict__ v2, const float* __restrict__ g2,
    const float* __restrict__ v3, const float* __restrict__ g3,
    float* __restrict__ ws)
{
  int blk = blockIdx.x;
  if (blk == 3072) {
    if (threadIdx.x == 0) {
      double beta = 0.1102 * (2.285 * 5.0 * M_PI * 1.2 + 7.95 - 8.7);
      double ib = i0d(beta);
      double f[12]; double s = 0.0;
      for (int n = 0; n < 12; ++n) {
        double r = ((double)n - 5.5) / 5.5;
        double w = i0d(beta * sqrt(fmax(0.0, 1.0 - r * r))) / ib;
        double tt = ((double)n - 5.5) * 0.5;
        double sc = sin(M_PI * tt) / (M_PI * tt);
        f[n] = 0.5 * w * sc;
        s += f[n];
      }
      for (int n = 0; n < 12; ++n) ws[OFF_FILT + n] = (float)(f[n] / s);
    }
    return;
  }
  const float* v; const float* g; int len; float* out;
  if (blk < 512)       { v = v1 + (size_t)blk * 3584;        g = g1 + blk;        len = 3584; out = ws + OFF_S1 + blk; }
  else if (blk < 2560) { int m = blk - 512;  v = v2 + (size_t)m * 512;  g = g2 + m; len = 512;  out = ws + OFF_S2 + m; }
  else                 { int m = blk - 2560; v = v3 + (size_t)m * 2048; g = g3 + m; len = 2048; out = ws + OFF_S3 + m; }
  float s = 0.f;
  for (int i = threadIdx.x; i < len; i += 256) { float x = v[i]; s = fmaf(x, x, s); }
  #pragma unroll
  for (int off = 32; off > 0; off >>= 1) s += __shfl_down(s, off);
  __shared__ float red[4];
  int lane = threadIdx.x & 63, w = threadIdx.x >> 6;
  if (lane == 0) red[w] = s;
  __syncthreads();
  if (threadIdx.x == 0) {
    float tot = red[0] + red[1] + red[2] + red[3];
    *out = g[0] / sqrtf(tot);
  }
}

// split-K weight fusion
__global__ __launch_bounds__(256) void fuse_w(
    const float* __restrict__ v2, const float* __restrict__ v3,
    float* __restrict__ ws)
{
  const float* s2 = ws + OFF_S2;
  float* wfp = ws + OFF_WFP;
  __shared__ float a[32][68];
  __shared__ float bsh[32][68];
  int i0 = blockIdx.x * 64, o0 = blockIdx.y * 64;
  int mbase = blockIdx.z * 256;
  int tid = threadIdx.x;
  int ii = tid & 15, io = tid >> 4;
  float acc[4][4] = {};
  for (int m0 = mbase; m0 < mbase + 256; m0 += 32) {
    for (int idx = tid; idx < 2048; idx += 256) {
      int o_l = idx >> 5, mm = idx & 31;
      a[mm][o_l] = v3[(size_t)(o0 + o_l) * 2048 + m0 + mm];
    }
    for (int idx = tid; idx < 2048; idx += 256) {
      int mm = idx >> 6, i_l = idx & 63;
      bsh[mm][i_l] = v2[(size_t)(m0 + mm) * 512 + i0 + i_l] * s2[m0 + mm];
    }
    __syncthreads();
    #pragma unroll 8
    for (int mm = 0; mm < 32; ++mm) {
      float4 av = *(const float4*)&a[mm][io * 4];
      float4 bv = *(const float4*)&bsh[mm][ii * 4];
      float ar[4] = {av.x, av.y, av.z, av.w};
      float br[4] = {bv.x, bv.y, bv.z, bv.w};
      #pragma unroll
      for (int p = 0; p < 4; ++p)
        #pragma unroll
        for (int q = 0; q < 4; ++q)
          acc[p][q] = fmaf(ar[p], br[q], acc[p][q]);
    }
    __syncthreads();
  }
  float* wout = wfp + (size_t)blockIdx.z * 512 * 512;
  #pragma unroll
  for (int p = 0; p < 4; ++p) {
    int o = o0 + io * 4 + p;
    float4 r;
    r.x = acc[p][0]; r.y = acc[p][1]; r.z = acc[p][2]; r.w = acc[p][3];
    *(float4*)&wout[(size_t)o * 512 + i0 + ii * 4] = r;
  }
}

// reduce 8 partials, scale by s3, pack into frag-linear order:
// idx = (((o_t*16+ics)*4+m)*512 + lane*8 + j
// o = o_t*64+m*16+(lane&15), ic = ics*32+(lane>>4)*8+j
__global__ __launch_bounds__(256) void wfpack(
    const float* __restrict__ wfp, const float* __restrict__ s3,
    bf16_t* __restrict__ wpf)
{
  int idx = blockIdx.x * 256 + threadIdx.x;   // 512*512
  int low = idx & 511;
  int lane = low >> 3, j = low & 7;
  int q = idx >> 9;
  int m = q & 3;
  int sdx = q >> 2;
  int o_t = sdx >> 4, ics = sdx & 15;
  int o = o_t * 64 + m * 16 + (lane & 15);
  int ic = ics * 32 + (lane >> 4) * 8 + j;
  int src = o * 512 + ic;
  float s = 0.f;
  #pragma unroll
  for (int kc = 0; kc < 8; ++kc) s += wfp[(size_t)kc * 262144 + src];
  wpf[idx] = f2bf(s * s3[o]);
}

// pack v1*s1 frag-linear:
// idx = ((((o_t*16+ics)*7+tap)*4+m)*512 + lane*8 + j
__global__ __launch_bounds__(256) void wprep1(
    const float* __restrict__ v1, const float* __restrict__ s1w,
    bf16_t* __restrict__ wp)
{
  int idx = blockIdx.x * 256 + threadIdx.x;   // 7*512*512 = 1835008
  int low = idx & 511;
  int lane = low >> 3, j = low & 7;
  int q = idx >> 9;
  int m = q & 3;
  int q2 = q >> 2;
  int tap = q2 % 7;
  int sdx = q2 / 7;
  int o_t = sdx >> 4, ics = sdx & 15;
  int o = o_t * 64 + m * 16 + (lane & 15);
  int ic = ics * 32 + (lane >> 4) * 8 + j;
  wp[idx] = f2bf(v1[((size_t)o * 512 + ic) * 7 + tap] * s1w[o]);
}

// fused act1d (round-5 proven)
template <typename T>
__global__ __launch_bounds__(256) void act_kernel(
    const T* __restrict__ src, bf16_t* __restrict__ dst,
    const float* __restrict__ alpha, const float* __restrict__ beta,
    const float* __restrict__ filt_g)
{
  __shared__ float xs[522];
  __shared__ float ys[1034];
  __shared__ float F[12];
  int t0 = blockIdx.x * 512;
  int c = blockIdx.y;
  int b = blockIdx.z;
  const T* row = src + ((size_t)b * C_CH + c) * T_LEN;
  bf16_t* orow = dst + ((size_t)b * C_CH + c) * T_LEN;
  int tid = threadIdx.x;
  if (tid < 12) F[tid] = filt_g[tid];
  float ea = __expf(alpha[c]);
  float ibv = 1.0f / (__expf(beta[c]) + 1e-9f);
  for (int i = tid; i < 522; i += 256) {
    int g = t0 - 5 + i;
    g = min(max(g, 0), T_LEN - 1);
    xs[i] = loadv(row, g);
  }
  __syncthreads();
  for (int m = tid; m < 1034; m += 256) {
    int n = 2 * t0 - 5 + m;
    n = min(max(n, 0), 2 * T_LEN - 1);
    int tp = n >> 1;
    int base = tp - t0;
    float s = 0.f;
    if (n & 1) {
      #pragma unroll
      for (int u = 0; u < 6; ++u) s = fmaf(xs[base + 3 + u], F[10 - 2 * u], s);
    } else {
      #pragma unroll
      for (int u = 0; u < 6; ++u) s = fmaf(xs[base + 2 + u], F[11 - 2 * u], s);
    }
    float y = 2.f * s;
    float sn = __sinf(y * ea);
    ys[m] = fmaf(ibv * sn, sn, y);
  }
  __syncthreads();
  for (int tl = tid; tl < 512; tl += 256) {
    float h = 0.f;
    #pragma unroll
    for (int k = 0; k < 12; ++k) h = fmaf(F[k], ys[2 * tl + k], h);
    orow[t0 + tl] = f2bf(h);
  }
}

// conv K=7, 512->512, zero-pad-3, MFMA 16x16x32 bf16, NCH I/O.
// Block 64(o) x 256(t); 4 waves each 64o x 64t (m4 x n4).
// Per 32-ic step: W frag-linear 28KB + X pitch-80 rows 21.25KB in LDS.
// Grid (16,8,4)=512 blocks, 3 blocks/CU.
__global__ __launch_bounds__(256, 3) void conv7_mfma(
    const bf16_t* __restrict__ src, const bf16_t* __restrict__ wp,
    bf16_t* __restrict__ dst)
{
  __shared__ __align__(16) char LDS[7 * 4096 + 272 * 80];   // W | X
  char* Wl = LDS;
  char* Xl = LDS + 7 * 4096;
  const int t0 = blockIdx.x * 256;
  const int o_t = blockIdx.y;
  const int o0 = o_t * 64;
  const int b  = blockIdx.z;
  const int tid = threadIdx.x;
  const int wave = tid >> 6;
  const int lane = tid & 63;
  const int l15 = lane & 15, lhi = lane >> 4;
  const int trow0 = wave * 64;
  f32x4 acc[4][4];
  #pragma unroll
  for (int m = 0; m < 4; ++m)
    #pragma unroll
    for (int n = 0; n < 4; ++n)
      acc[m][n] = (f32x4){0.f, 0.f, 0.f, 0.f};

  const bf16_t* xg = src + (size_t)b * C_CH * T_LEN;

  for (int ics = 0; ics < 16; ++ics) {
    const int cb = ics * 32;
    __syncthreads();
    // stage W: linear 28672B copy (frag-packed in global)
    {
      const bf16_t* wsrc = wp + (size_t)(o_t * 16 + ics) * 14336;
      #pragma unroll
      for (int it = 0; it < 7; ++it) {
        int u = it * 256 + tid;
        *(bf16x8*)(Wl + u * 16) = *(const bf16x8*)(wsrc + (size_t)u * 8);
      }
    }
    // stage X: rows [t0-8, t0+264) x 32 ic, transposed [t][ic], pitch 80B
    for (int u = tid; u < 1088; u += 256) {
      int ic = u & 31;
      int ro = u >> 5;
      int gt0 = t0 - 8 + ro * 8;
      const bf16_t* gp = xg + (size_t)(cb + ic) * T_LEN + gt0;
      bf16_t vals[8];
      if (gt0 >= 0 && gt0 + 8 <= T_LEN) {
        bf16x8 v = *(const bf16x8*)gp;
        #pragma unroll
        for (int i = 0; i < 8; ++i) vals[i] = (bf16_t)v[i];
      } else {
        #pragma unroll
        for (int i = 0; i < 8; ++i) {
          int gt = gt0 + i;
          vals[i] = (gt >= 0 && gt < T_LEN) ? gp[i] : (bf16_t)0;
        }
      }
      #pragma unroll
      for (int i = 0; i < 8; ++i)
        *(bf16_t*)(Xl + (ro * 8 + i) * 80 + ic * 2) = vals[i];
    }
    __syncthreads();
    #pragma unroll
    for (int tap = 0; tap < 7; ++tap) {
      bf16x8 a[4];
      #pragma unroll
      for (int m = 0; m < 4; ++m)
        a[m] = *(const bf16x8*)(Wl + tap * 4096 + m * 1024 + lane * 16);
      bf16x8 bq[4];
      #pragma unroll
      for (int n = 0; n < 4; ++n) {
        int rl = trow0 + n * 16 + l15 + tap + 5;
        bq[n] = *(const bf16x8*)(Xl + rl * 80 + lhi * 16);
      }
      #pragma unroll
      for (int m = 0; m < 4; ++m)
        #pragma unroll
        for (int n = 0; n < 4; ++n)
          acc[m][n] = __builtin_amdgcn_mfma_f32_16x16x32_bf16(a[m], bq[n], acc[m][n], 0, 0, 0);
    }
  }
  bf16_t* drow = dst + (size_t)b * C_CH * T_LEN;
  #pragma unroll
  for (int m = 0; m < 4; ++m)
    #pragma unroll
    for (int n = 0; n < 4; ++n) {
      int t = t0 + trow0 + n * 16 + l15;
      #pragma unroll
      for (int r = 0; r < 4; ++r) {
        int o = o0 + m * 16 + lhi * 4 + r;
        drow[(size_t)o * T_LEN + t] = f2bf(acc[m][n][r]);
      }
    }
}

// out = x + wf @ h (1x1 512->512), NCH I/O, residual f32 out.
// Block 64o x 256t, 4 waves of 64o x 64t; W frag-linear 4KB + X pitch-80 20KB.
__global__ __launch_bounds__(256, 4) void gemm_mfma(
    const bf16_t* __restrict__ src, const bf16_t* __restrict__ wp,
    const float* __restrict__ x, float* __restrict__ out)
{
  __shared__ __align__(16) char LDS[4096 + 256 * 80];
  char* Wl = LDS;
  char* Xl = LDS + 4096;
  const int t0 = blockIdx.x * 256;
  const int o_t = blockIdx.y;
  const int o0 = o_t * 64;
  const int b  = blockIdx.z;
  const int tid = threadIdx.x;
  const int wave = tid >> 6;
  const int lane = tid & 63;
  const int l15 = lane & 15, lhi = lane >> 4;
  const int trow0 = wave * 64;
  f32x4 acc[4][4];
  #pragma unroll
  for (int m = 0; m < 4; ++m)
    #pragma unroll
    for (int n = 0; n < 4; ++n)
      acc[m][n] = (f32x4){0.f, 0.f, 0.f, 0.f};

  const bf16_t* xg = src + (size_t)b * C_CH * T_LEN;

  for (int ics = 0; ics < 16; ++ics) {
    const int cb = ics * 32;
    __syncthreads();
    {
      const bf16_t* wsrc = wp + (size_t)(o_t * 16 + ics) * 2048;
      *(bf16x8*)(Wl + tid * 16) = *(const bf16x8*)(wsrc + (size_t)tid * 8);
    }
    #pragma unroll
    for (int it = 0; it < 4; ++it) {
      int u = it * 256 + tid;
      int ic = u & 31;
      int ro = u >> 5;
      const bf16_t* gp = xg + (size_t)(cb + ic) * T_LEN + t0 + ro * 8;
      bf16x8 v = *(const bf16x8*)gp;
      #pragma unroll
      for (int i = 0; i < 8; ++i)
        *(bf16_t*)(Xl + (ro * 8 + i) * 80 + ic * 2) = (bf16_t)v[i];
    }
    __syncthreads();
    bf16x8 a[4];
    #pragma unroll
    for (int m = 0; m < 4; ++m)
      a[m] = *(const bf16x8*)(Wl + m * 1024 + lane * 16);
    bf16x8 bq[4];
    #pragma unroll
    for (int n = 0; n < 4; ++n) {
      int rl = trow0 + n * 16 + l15;
      bq[n] = *(const bf16x8*)(Xl + rl * 80 + lhi * 16);
    }
    #pragma unroll
    for (int m = 0; m < 4; ++m)
      #pragma unroll
      for (int n = 0; n < 4; ++n)
        acc[m][n] = __builtin_amdgcn_mfma_f32_16x16x32_bf16(a[m], bq[n], acc[m][n], 0, 0, 0);
  }
  #pragma unroll
  for (int m = 0; m < 4; ++m)
    #pragma unroll
    for (int n = 0; n < 4; ++n) {
      int t = t0 + trow0 + n * 16 + l15;
      #pragma unroll
      for (int r = 0; r < 4; ++r) {
        int o = o0 + m * 16 + lhi * 4 + r;
        size_t off = ((size_t)b * C_CH + o) * T_LEN + t;
        out[off] = x[off] + acc[m][n][r];
      }
    }
}

extern "C" void kernel_launch(void* const* d_in, const int* in_sizes, int n_in,
                              void* d_out, int out_size, void* d_ws, size_t ws_size,
                              hipStream_t stream) {
  const float* x  = (const float*)d_in[0];
  const float* a1 = (const float*)d_in[1];
  const float* b1 = (const float*)d_in[2];
  const float* v1 = (const float*)d_in[3];
  const float* g1 = (const float*)d_in[4];
  const float* a2 = (const float*)d_in[5];
  const float* b2 = (const float*)d_in[6];
  const float* v2 = (const float*)d_in[7];
  const float* g2 = (const float*)d_in[8];
  const float* v3 = (const float*)d_in[9];
  const float* g3 = (const float*)d_in[10];
  float* out = (float*)d_out;
  float* ws  = (float*)d_ws;
  bf16_t* wp1 = (bf16_t*)(ws + OFF_WP1);
  bf16_t* wpf = (bf16_t*)(ws + OFF_WPF);
  bf16_t* h1  = (bf16_t*)(ws + OFF_H1);
  bf16_t* h2  = (bf16_t*)(ws + OFF_H2);
  bf16_t* h3  = (bf16_t*)(ws + OFF_H3);

  init_consts<<<3073, 256, 0, stream>>>(v1, g1, v2, g2, v3, g3, ws);
  fuse_w<<<dim3(8, 8, 8), 256, 0, stream>>>(v2, v3, ws);
  wfpack<<<1024, 256, 0, stream>>>(ws + OFF_WFP, ws + OFF_S3, wpf);
  wprep1<<<7168, 256, 0, stream>>>(v1, ws + OFF_S1, wp1);
  act_kernel<float><<<dim3(8, 512, 4), 256, 0, stream>>>(x, h1, a1, b1, ws + OFF_FILT);
  conv7_mfma<<<dim3(16, 8, 4), 256, 0, stream>>>(h1, wp1, h2);
  act_kernel<bf16_t><<<dim3(8, 512, 4), 256, 0, stream>>>(h2, h3, a2, b2, ws + OFF_FILT);
  gemm_mfma<<<dim3(16, 8, 4), 256, 0, stream>>>(h3, wpf, x, out);
}